// Round 5
// baseline (238.890 us; speedup 1.0000x reference)
//
#include <hip/hip_runtime.h>
#include <hip/hip_bf16.h>
#include <math.h>

#define NB 128
#define NS 256
#define NH 768
#define NL 24
#define ASTR 68   // A-tile LDS stride (words): 68%32=4 -> 2-way banks, 16B-aligned rows
#define NW 5      // backtrack windows per batch

// ---------------- Kernel A: emissions = sigmoid(tf[b,t+1,:] @ W + b) for t < n_b ----
// (unchanged from round 4: W chunk in LDS, broadcast ds_read_b128, 32-token tiles)
__global__ __launch_bounds__(256) void ner_emis(
    const float* __restrict__ tf, const int* __restrict__ tlm,
    const float* __restrict__ W, const float* __restrict__ bias,
    float* __restrict__ E)
{
    const int b    = blockIdx.x >> 3;
    const int tile = (blockIdx.x & 7) << 5;
    const int tid  = threadIdx.x;
    if (tlm[b*NS + tile] == 0) return;

    __shared__ float lds[8*32*25];
    float* As = lds;
    float* Ws = lds + 32*ASTR;
    float* Pr = lds;

    const int tok  = tid & 15;
    const int ksub = tid >> 4;
    const int kk   = ksub << 2;
    const int rot  = ksub & 3;

    float acc0[NL], acc1[NL];
    #pragma unroll
    for (int l = 0; l < NL; ++l) { acc0[l] = 0.f; acc1[l] = 0.f; }

    const float* tfb = tf + (size_t)(b*NS)*NH;

    for (int kc0 = 0; kc0 < NH; kc0 += 64) {
        #pragma unroll
        for (int i = 0; i < 2; ++i) {
            int idx  = tid + (i << 8);
            int row  = idx >> 4;
            int c4   = idx & 15;
            int trow = tile + row + 1;
            if (trow > 255) trow = 255;
            float4 v = *(const float4*)(tfb + (size_t)trow*NH + kc0 + (c4 << 2));
            float* dst = As + row*ASTR + (c4 << 2);
            dst[0] = v.x; dst[1] = v.y; dst[2] = v.z; dst[3] = v.w;
        }
        {
            const float4* wsrc = (const float4*)(W + (size_t)kc0*NL);
            float4* wdst = (float4*)Ws;
            for (int i = tid; i < 384; i += 256) wdst[i] = wsrc[i];
        }
        __syncthreads();

        const float* A0 = As + tok*ASTR + kk;
        const float* A1 = A0 + 16*ASTR;
        const float* Wr = Ws + kk*NL;
        #pragma unroll
        for (int s = 0; s < 4; ++s) {
            const int j = (s + rot) & 3;
            float a0 = A0[j];
            float a1 = A1[j];
            const float4* w4 = (const float4*)(Wr + j*NL);
            float wv[NL];
            #pragma unroll
            for (int i = 0; i < 6; ++i) {
                float4 w = w4[i];
                wv[4*i+0] = w.x; wv[4*i+1] = w.y; wv[4*i+2] = w.z; wv[4*i+3] = w.w;
            }
            #pragma unroll
            for (int l = 0; l < NL; ++l) {
                acc0[l] = fmaf(a0, wv[l], acc0[l]);
                acc1[l] = fmaf(a1, wv[l], acc1[l]);
            }
        }
        __syncthreads();
    }

    if (ksub >= 8) {
        float* p = Pr + ((ksub-8)*32 + tok)*25;
        float* q = p + 16*25;
        #pragma unroll
        for (int l = 0; l < NL; ++l) { p[l] = acc0[l]; q[l] = acc1[l]; }
    }
    __syncthreads();
    if (ksub < 8) {
        const float* p = Pr + (ksub*32 + tok)*25;
        const float* q = p + 16*25;
        #pragma unroll
        for (int l = 0; l < NL; ++l) { acc0[l] += p[l]; acc1[l] += q[l]; }
    }
    __syncthreads();
    if (ksub < 8) {
        float* p = Pr + (ksub*32 + tok)*25;
        float* q = p + 16*25;
        #pragma unroll
        for (int l = 0; l < NL; ++l) { p[l] = acc0[l]; q[l] = acc1[l]; }
    }
    __syncthreads();

    const int* tm = tlm + b*NS + tile;
    float* Eb = E + (size_t)(b*NS + tile)*NL;
    #pragma unroll
    for (int i = 0; i < 3; ++i) {
        int o = tid + (i << 8);
        int t = o / NL, l = o % NL;
        if (tm[t]) {
            float s = 0.f;
            #pragma unroll
            for (int ks = 0; ks < 8; ++ks)
                s += Pr[(ks*32 + t)*25 + l];
            float x = s + bias[l];
            Eb[t*NL + l] = 1.0f/(1.0f + expf(-x));
        }
    }
}

// ---------------- Kernel B: Viterbi, 2 batches per block (per wave-0), 64 blocks ----
// lanes 0-23 = tags of batch 2*pb, lanes 32-55 = tags of batch 2*pb+1.
// Broadcast of the 24 scores via ds_bpermute (per-half), no readlane SGPR hazards.
__global__ __launch_bounds__(256) void ner_viterbi(
    const float* __restrict__ E, const int* __restrict__ tlm,
    const float* __restrict__ trans, const float* __restrict__ st,
    const float* __restrict__ en, int* __restrict__ out)
{
    const int tid = threadIdx.x;
    const int pb  = blockIdx.x;                 // pair index 0..63

    __shared__ float scl[2*NS*NL];              // 49.2 KB  score history, both batches
    __shared__ float Tt[NL*NL];                 // 2.3 KB   Tt[c*24+p] = T[p][c]
    __shared__ float fin_s[2*NL];
    __shared__ unsigned char tr_s[2][NL][NS];   // 12.3 KB
    __shared__ int chosen_s[2][NW+1];
    __shared__ int nsh[2], ltag[2];

    for (int i = tid; i < NL*NL; i += 256) {
        int c = i / NL, p = i % NL;
        Tt[i] = trans[p*NL + c];
    }
    if (tid < 128) {                            // n per batch: waves 0,1 halves
        const int wv = tid >> 6, ln = tid & 63;
        const int bb = 2*pb + wv;
        int a = tlm[bb*NS+ln] + tlm[bb*NS+ln+64] + tlm[bb*NS+ln+128] + tlm[bb*NS+ln+192];
        #pragma unroll
        for (int off = 32; off > 0; off >>= 1) a += __shfl_down(a, off, 64);
        if (ln == 0) nsh[wv] = a;
    }
    __syncthreads();
    const int nA = nsh[0], nB = nsh[1];
    const int nmax = __builtin_amdgcn_readfirstlane(nA > nB ? nA : nB);

    // ---- forward: wave 0 only; SIMD over two batches ----
    if (tid < 64) {
        const int lane  = tid;
        const int half  = lane >> 5;            // 0: batch A, 1: batch B
        const int c     = lane & 31;            // tag (garbage for c>=24)
        const int cef   = (c < 24) ? c : 23;
        const bool valid = (c < 24);
        const int myb   = 2*pb + half;
        const int hbase = half << 7;            // bpermute byte base: half*32 lanes *4
        const int nh    = half ? nB : nA;       // per-lane length

        float Tc[NL];
        #pragma unroll
        for (int p = 0; p < NL; ++p) Tc[p] = trans[p*NL + cef];

        const float* Eb = E + (size_t)(myb*NS)*NL + cef;
        float* sbase = scl + (half*NS)*NL;

        float sv = st[cef] + Eb[0];
        if (valid) sbase[c] = sv;

        auto bperm = [](int idx, float v) {
            return __int_as_float(__builtin_amdgcn_ds_bpermute(idx, __float_as_int(v)));
        };

        auto step = [&](int t, float em) {
            float cand[NL];
            #pragma unroll
            for (int p = 0; p < NL; ++p)
                cand[p] = bperm(hbase + 4*p, sv) + Tc[p];
            float m0 = fmaxf(fmaxf(cand[0],  cand[1]),  cand[2]);
            float m1 = fmaxf(fmaxf(cand[3],  cand[4]),  cand[5]);
            float m2 = fmaxf(fmaxf(cand[6],  cand[7]),  cand[8]);
            float m3 = fmaxf(fmaxf(cand[9],  cand[10]), cand[11]);
            float m4 = fmaxf(fmaxf(cand[12], cand[13]), cand[14]);
            float m5 = fmaxf(fmaxf(cand[15], cand[16]), cand[17]);
            float m6 = fmaxf(fmaxf(cand[18], cand[19]), cand[20]);
            float m7 = fmaxf(fmaxf(cand[21], cand[22]), cand[23]);
            float q0 = fmaxf(fmaxf(m0, m1), m2);
            float q1 = fmaxf(fmaxf(m3, m4), m5);
            float q2 = fmaxf(m6, m7);
            float best = fmaxf(fmaxf(q0, q1), q2);
            float nsv = best + em;
            sv = (t < nh) ? nsv : sv;           // frozen past this batch's length
            if (valid) sbase[t*NL + c] = sv;
        };

        float emb[8];
        #pragma unroll
        for (int j = 0; j < 8; ++j) {
            int tp = 1 + j; if (tp > NS-1) tp = NS-1;
            emb[j] = Eb[(size_t)tp*NL];
        }
        for (int t0 = 1; t0 < nmax; t0 += 8) {
            float emc[8];
            #pragma unroll
            for (int j = 0; j < 8; ++j) emc[j] = emb[j];
            #pragma unroll
            for (int j = 0; j < 8; ++j) {       // next group's prefetch
                int tp = t0 + 8 + j; if (tp > NS-1) tp = NS-1;
                emb[j] = Eb[(size_t)tp*NL];
            }
            #pragma unroll
            for (int j = 0; j < 8; ++j) {
                int t = t0 + j;
                if (t >= nmax) break;           // uniform
                step(t, emc[j]);
            }
        }
        if (valid) fin_s[half*NL + c] = sv + en[cef];
    }
    __syncthreads();

    if (tid < 2) {                              // argmax(final), first-max tie rule
        const float* f = fin_s + tid*NL;
        float bv = f[0]; int bt = 0;
        #pragma unroll
        for (int cc = 1; cc < 24; ++cc) { if (f[cc] > bv) { bv = f[cc]; bt = cc; } }
        ltag[tid] = bt;
    }
    __syncthreads();

    // ---- backtrack: 2 batches x NW windows x 24 hypotheses = 240 threads ----
    if (tid < 2*NW*24) {
        int g = tid;
        const int bb = g / (NW*24); g -= bb*NW*24;
        const int w  = g / 24 + 1;
        const int h  = g % 24;
        const int n  = nsh[bb];
        if (n > 1) {
            const int K = (n - 1 + NW - 1) / NW;
            int tlo = (w-1)*K; if (tlo > n-1) tlo = n-1;
            int thi = w*K;     if (thi > n-1) thi = n-1;
            const float* sbase = scl + (bb*NS)*NL;
            int cur = h;
            for (int t = thi; t > tlo; --t) {
                const float4* sp = (const float4*)(sbase + (t-1)*NL);
                const float4* up = (const float4*)(Tt + cur*NL);
                float cand[NL];
                #pragma unroll
                for (int i = 0; i < 6; ++i) {
                    float4 s = sp[i], u = up[i];
                    cand[4*i+0] = s.x + u.x;    // bitwise-identical to forward cand
                    cand[4*i+1] = s.y + u.y;
                    cand[4*i+2] = s.z + u.z;
                    cand[4*i+3] = s.w + u.w;
                }
                float best = cand[0]; int arg = 0;
                #pragma unroll
                for (int p = 1; p < 24; ++p) { if (cand[p] > best) { best = cand[p]; arg = p; } }
                tr_s[bb][h][t-1] = (unsigned char)arg;
                cur = arg;
            }
        }
    }
    __syncthreads();

    if (tid < 2) {                              // stitch windows per batch
        const int bb = tid;
        const int n  = nsh[bb];
        const int K  = (n > 1) ? (n - 1 + NW - 1) / NW : 1;
        int cur = ltag[bb];
        for (int w = NW; w >= 1; --w) {
            chosen_s[bb][w] = cur;
            int tlo = (w-1)*K; if (tlo > n-1) tlo = n-1;
            int thi = w*K;     if (thi > n-1) thi = n-1;
            if (thi > tlo) cur = tr_s[bb][cur][tlo];
        }
    }
    __syncthreads();

    {   // emit both batches; t >= n-1 -> last_tag (identity backpointers on pad)
        const int t = tid;
        #pragma unroll
        for (int bb = 0; bb < 2; ++bb) {
            const int n = nsh[bb];
            const int K = (n > 1) ? (n - 1 + NW - 1) / NW : 1;
            int tag;
            if (t >= n-1) tag = ltag[bb];
            else { int w = t / K + 1; tag = tr_s[bb][chosen_s[bb][w]][t]; }
            out[(2*pb + bb)*NS + t] = tag;
        }
    }
}

extern "C" void kernel_launch(void* const* d_in, const int* in_sizes, int n_in,
                              void* d_out, int out_size, void* d_ws, size_t ws_size,
                              hipStream_t stream) {
    const float* tf    = (const float*)d_in[0];
    const int*   tlm   = (const int*)  d_in[2];   // true_label_mask
    const float* W     = (const float*)d_in[3];
    const float* bias  = (const float*)d_in[4];
    const float* trans = (const float*)d_in[5];
    const float* st    = (const float*)d_in[6];
    const float* en    = (const float*)d_in[7];
    float* E = (float*)d_ws;                      // [128,256,24] fp32 = 3.1 MB

    ner_emis<<<dim3(NB*8), dim3(256), 0, stream>>>(tf, tlm, W, bias, E);
    ner_viterbi<<<dim3(NB/2), dim3(256), 0, stream>>>(E, tlm, trans, st, en, (int*)d_out);
}

// Round 6
// 230.939 us; speedup vs baseline: 1.0344x; 1.0344x over previous
//
#include <hip/hip_runtime.h>
#include <hip/hip_bf16.h>
#include <math.h>

#define NB 128
#define NS 256
#define NH 768
#define NL 24
#define ASTR 68   // A-tile LDS stride (words): 68%32=4 -> 2-way banks, 16B-aligned rows
#define NW 10     // backtrack windows

// ---------------- Kernel A: emissions = sigmoid(tf[b,t+1,:] @ W + b) for t < n_b ----
// (unchanged: W chunk in LDS, broadcast ds_read_b128, 32-token tiles, grid 1024)
__global__ __launch_bounds__(256) void ner_emis(
    const float* __restrict__ tf, const int* __restrict__ tlm,
    const float* __restrict__ W, const float* __restrict__ bias,
    float* __restrict__ E)
{
    const int b    = blockIdx.x >> 3;
    const int tile = (blockIdx.x & 7) << 5;
    const int tid  = threadIdx.x;
    if (tlm[b*NS + tile] == 0) return;

    __shared__ float lds[8*32*25];
    float* As = lds;
    float* Ws = lds + 32*ASTR;
    float* Pr = lds;

    const int tok  = tid & 15;
    const int ksub = tid >> 4;
    const int kk   = ksub << 2;
    const int rot  = ksub & 3;

    float acc0[NL], acc1[NL];
    #pragma unroll
    for (int l = 0; l < NL; ++l) { acc0[l] = 0.f; acc1[l] = 0.f; }

    const float* tfb = tf + (size_t)(b*NS)*NH;

    for (int kc0 = 0; kc0 < NH; kc0 += 64) {
        #pragma unroll
        for (int i = 0; i < 2; ++i) {
            int idx  = tid + (i << 8);
            int row  = idx >> 4;
            int c4   = idx & 15;
            int trow = tile + row + 1;
            if (trow > 255) trow = 255;
            float4 v = *(const float4*)(tfb + (size_t)trow*NH + kc0 + (c4 << 2));
            float* dst = As + row*ASTR + (c4 << 2);
            dst[0] = v.x; dst[1] = v.y; dst[2] = v.z; dst[3] = v.w;
        }
        {
            const float4* wsrc = (const float4*)(W + (size_t)kc0*NL);
            float4* wdst = (float4*)Ws;
            for (int i = tid; i < 384; i += 256) wdst[i] = wsrc[i];
        }
        __syncthreads();

        const float* A0 = As + tok*ASTR + kk;
        const float* A1 = A0 + 16*ASTR;
        const float* Wr = Ws + kk*NL;
        #pragma unroll
        for (int s = 0; s < 4; ++s) {
            const int j = (s + rot) & 3;
            float a0 = A0[j];
            float a1 = A1[j];
            const float4* w4 = (const float4*)(Wr + j*NL);
            float wv[NL];
            #pragma unroll
            for (int i = 0; i < 6; ++i) {
                float4 w = w4[i];
                wv[4*i+0] = w.x; wv[4*i+1] = w.y; wv[4*i+2] = w.z; wv[4*i+3] = w.w;
            }
            #pragma unroll
            for (int l = 0; l < NL; ++l) {
                acc0[l] = fmaf(a0, wv[l], acc0[l]);
                acc1[l] = fmaf(a1, wv[l], acc1[l]);
            }
        }
        __syncthreads();
    }

    if (ksub >= 8) {
        float* p = Pr + ((ksub-8)*32 + tok)*25;
        float* q = p + 16*25;
        #pragma unroll
        for (int l = 0; l < NL; ++l) { p[l] = acc0[l]; q[l] = acc1[l]; }
    }
    __syncthreads();
    if (ksub < 8) {
        const float* p = Pr + (ksub*32 + tok)*25;
        const float* q = p + 16*25;
        #pragma unroll
        for (int l = 0; l < NL; ++l) { acc0[l] += p[l]; acc1[l] += q[l]; }
    }
    __syncthreads();
    if (ksub < 8) {
        float* p = Pr + (ksub*32 + tok)*25;
        float* q = p + 16*25;
        #pragma unroll
        for (int l = 0; l < NL; ++l) { p[l] = acc0[l]; q[l] = acc1[l]; }
    }
    __syncthreads();

    const int* tm = tlm + b*NS + tile;
    float* Eb = E + (size_t)(b*NS + tile)*NL;
    #pragma unroll
    for (int i = 0; i < 3; ++i) {
        int o = tid + (i << 8);
        int t = o / NL, l = o % NL;
        if (tm[t]) {
            float s = 0.f;
            #pragma unroll
            for (int ks = 0; ks < 8; ++ks)
                s += Pr[(ks*32 + t)*25 + l];
            float x = s + bias[l];
            Eb[t*NL + l] = 1.0f/(1.0f + expf(-x));
        }
    }
}

// ---------------- Kernel B: masked Viterbi decode, one block (256 thr) per batch ----
// Forward on 24 lanes only (exec set once): readlane broadcast (VALU pipe, no LDS
// round-trip on the chain), max3 tree depth 3, clamp-free 8-deep emission prefetch.
__global__ __launch_bounds__(256) void ner_viterbi(
    const float* __restrict__ E, const int* __restrict__ tlm,
    const float* __restrict__ trans, const float* __restrict__ st,
    const float* __restrict__ en, int* __restrict__ out)
{
    const int tid = threadIdx.x;
    const int b   = blockIdx.x;
    const int bS  = b*NS;

    __shared__ float Esh[262*NL];           // 25.1 KB (padded: clamp-free prefetch)
    __shared__ float scl[NS*NL];            // 24.6 KB score history
    __shared__ float Tt[NL*NL];             // Tt[c*24+p] = T[p][c]
    __shared__ float fin[NL];
    __shared__ unsigned char tr_s[NL][NS];  // 6.1 KB trace[hypothesis][t]
    __shared__ int chosen[NW+2];
    __shared__ int nsh, ltag;

    {
        const float4* src = (const float4*)(E + (size_t)bS*NL);
        float4* dst = (float4*)Esh;
        #pragma unroll
        for (int j = 0; j < 6; ++j) dst[tid + (j << 8)] = src[tid + (j << 8)];
    }
    for (int i = tid; i < NL*NL; i += 256) {
        int c = i / NL, p = i % NL;
        Tt[i] = trans[p*NL + c];
    }
    if (tid < 64) {   // n = lengths[b]-2 (contiguous prefix mask)
        int a = tlm[bS+tid] + tlm[bS+tid+64] + tlm[bS+tid+128] + tlm[bS+tid+192];
        #pragma unroll
        for (int off = 32; off > 0; off >>= 1) a += __shfl_down(a, off, 64);
        if (tid == 0) nsh = a;
    }
    __syncthreads();
    const int n = nsh;   // 1 <= n <= 254

    // ---- forward: 24 lanes of wave 0; chain = readlane + add + max3x3 + add ----
    if (tid < 24) {
        const int c = tid;
        float Tc[NL];
        #pragma unroll
        for (int p = 0; p < NL; ++p) Tc[p] = trans[p*NL + c];

        auto rl = [](float v, int p) {       // lane p -> SGPR (exec-independent)
            return __int_as_float(__builtin_amdgcn_readlane(__float_as_int(v), p));
        };

        float sv = st[c] + Esh[c];
        scl[c] = sv;

        auto step = [&](int t, float em) {
            float cand[NL];
            #pragma unroll
            for (int p = 0; p < NL; ++p) cand[p] = rl(sv, p) + Tc[p];
            float m0 = fmaxf(fmaxf(cand[0],  cand[1]),  cand[2]);
            float m1 = fmaxf(fmaxf(cand[3],  cand[4]),  cand[5]);
            float m2 = fmaxf(fmaxf(cand[6],  cand[7]),  cand[8]);
            float m3 = fmaxf(fmaxf(cand[9],  cand[10]), cand[11]);
            float m4 = fmaxf(fmaxf(cand[12], cand[13]), cand[14]);
            float m5 = fmaxf(fmaxf(cand[15], cand[16]), cand[17]);
            float m6 = fmaxf(fmaxf(cand[18], cand[19]), cand[20]);
            float m7 = fmaxf(fmaxf(cand[21], cand[22]), cand[23]);
            float q0 = fmaxf(fmaxf(m0, m1), m2);      // max3
            float q1 = fmaxf(fmaxf(m3, m4), m5);      // max3
            float q2 = fmaxf(m6, m7);
            sv = fmaxf(fmaxf(q0, q1), q2) + em;       // max3 + add
            scl[t*NL + c] = sv;                       // 24 distinct addrs, off chain
        };

        float emb[8];
        #pragma unroll
        for (int j = 0; j < 8; ++j) emb[j] = Esh[(1+j)*NL + c];   // rows 1..8 < 262
        int t0 = 1;
        for (; t0 + 8 <= n; t0 += 8) {
            float emc[8];
            #pragma unroll
            for (int j = 0; j < 8; ++j) emc[j] = emb[j];
            #pragma unroll
            for (int j = 0; j < 8; ++j) emb[j] = Esh[(t0+8+j)*NL + c]; // <=261: in-bounds
            #pragma unroll
            for (int j = 0; j < 8; ++j) step(t0 + j, emc[j]);
        }
        for (; t0 < n; ++t0) step(t0, Esh[t0*NL + c]);
        fin[c] = sv + en[c];
    }
    __syncthreads();

    if (tid == 0) {   // argmax(final), first-max tie rule like jnp.argmax
        float bv = fin[0]; int bt = 0;
        #pragma unroll
        for (int cc = 1; cc < 24; ++cc) { if (fin[cc] > bv) { bv = fin[cc]; bt = cc; } }
        ltag = bt;
    }
    __syncthreads();

    // ---- backtrack: NW windows x 24 hypotheses, recompute backpointers ----
    const int K = (n > 1) ? (n - 1 + NW - 1) / NW : 1;
    if (n > 1 && tid < NW*24) {
        const int w = tid / 24 + 1, h = tid % 24;
        int tlo = (w-1)*K; if (tlo > n-1) tlo = n-1;
        int thi = w*K;     if (thi > n-1) thi = n-1;
        int cur = h;
        for (int t = thi; t > tlo; --t) {
            const float4* sp = (const float4*)(scl + (t-1)*NL);
            const float4* up = (const float4*)(Tt + cur*NL);
            float cand[NL];
            #pragma unroll
            for (int i = 0; i < 6; ++i) {
                float4 s = sp[i], u = up[i];
                cand[4*i+0] = s.x + u.x;     // bitwise-identical to forward cand
                cand[4*i+1] = s.y + u.y;
                cand[4*i+2] = s.z + u.z;
                cand[4*i+3] = s.w + u.w;
            }
            float best = cand[0]; int arg = 0;
            #pragma unroll
            for (int p = 1; p < 24; ++p) { if (cand[p] > best) { best = cand[p]; arg = p; } }
            tr_s[h][t-1] = (unsigned char)arg;
            cur = arg;
        }
    }
    __syncthreads();

    if (tid == 0) {   // stitch windows
        int cur = ltag;
        for (int w = NW; w >= 1; --w) {
            chosen[w] = cur;
            int tlo = (w-1)*K; if (tlo > n-1) tlo = n-1;
            int thi = w*K;     if (thi > n-1) thi = n-1;
            if (thi > tlo) cur = tr_s[cur][tlo];
        }
    }
    __syncthreads();

    {   // emit path: t >= n-1 -> last_tag (identity backpointers on padding)
        const int t = tid;
        int tag;
        if (t >= n-1) tag = ltag;
        else { int w = t / K + 1; tag = tr_s[chosen[w]][t]; }
        out[bS + t] = tag;
    }
}

extern "C" void kernel_launch(void* const* d_in, const int* in_sizes, int n_in,
                              void* d_out, int out_size, void* d_ws, size_t ws_size,
                              hipStream_t stream) {
    const float* tf    = (const float*)d_in[0];
    const int*   tlm   = (const int*)  d_in[2];   // true_label_mask
    const float* W     = (const float*)d_in[3];
    const float* bias  = (const float*)d_in[4];
    const float* trans = (const float*)d_in[5];
    const float* st    = (const float*)d_in[6];
    const float* en    = (const float*)d_in[7];
    float* E = (float*)d_ws;                      // [128,256,24] fp32 = 3.1 MB

    ner_emis<<<dim3(NB*8), dim3(256), 0, stream>>>(tf, tlm, W, bias, E);
    ner_viterbi<<<dim3(NB), dim3(256), 0, stream>>>(E, tlm, trans, st, en, (int*)d_out);
}

// Round 7
// 214.962 us; speedup vs baseline: 1.1113x; 1.0743x over previous
//
#include <hip/hip_runtime.h>
#include <hip/hip_bf16.h>
#include <math.h>

#define NB 128
#define NS 256
#define NH 768
#define NL 24
#define ASTR 68   // A-tile LDS stride (words)
#define NW 10     // backtrack windows
#define SSTR 28   // scl/Tt row stride (words): 16B-aligned, 8 bank groups

// ---------------- Kernel A: emissions = sigmoid(tf[b,t+1,:] @ W + b) for t < n_b ----
// (unchanged: W chunk in LDS, broadcast ds_read_b128, 32-token tiles, grid 1024)
__global__ __launch_bounds__(256) void ner_emis(
    const float* __restrict__ tf, const int* __restrict__ tlm,
    const float* __restrict__ W, const float* __restrict__ bias,
    float* __restrict__ E)
{
    const int b    = blockIdx.x >> 3;
    const int tile = (blockIdx.x & 7) << 5;
    const int tid  = threadIdx.x;
    if (tlm[b*NS + tile] == 0) return;

    __shared__ float lds[8*32*25];
    float* As = lds;
    float* Ws = lds + 32*ASTR;
    float* Pr = lds;

    const int tok  = tid & 15;
    const int ksub = tid >> 4;
    const int kk   = ksub << 2;
    const int rot  = ksub & 3;

    float acc0[NL], acc1[NL];
    #pragma unroll
    for (int l = 0; l < NL; ++l) { acc0[l] = 0.f; acc1[l] = 0.f; }

    const float* tfb = tf + (size_t)(b*NS)*NH;

    for (int kc0 = 0; kc0 < NH; kc0 += 64) {
        #pragma unroll
        for (int i = 0; i < 2; ++i) {
            int idx  = tid + (i << 8);
            int row  = idx >> 4;
            int c4   = idx & 15;
            int trow = tile + row + 1;
            if (trow > 255) trow = 255;
            float4 v = *(const float4*)(tfb + (size_t)trow*NH + kc0 + (c4 << 2));
            float* dst = As + row*ASTR + (c4 << 2);
            dst[0] = v.x; dst[1] = v.y; dst[2] = v.z; dst[3] = v.w;
        }
        {
            const float4* wsrc = (const float4*)(W + (size_t)kc0*NL);
            float4* wdst = (float4*)Ws;
            for (int i = tid; i < 384; i += 256) wdst[i] = wsrc[i];
        }
        __syncthreads();

        const float* A0 = As + tok*ASTR + kk;
        const float* A1 = A0 + 16*ASTR;
        const float* Wr = Ws + kk*NL;
        #pragma unroll
        for (int s = 0; s < 4; ++s) {
            const int j = (s + rot) & 3;
            float a0 = A0[j];
            float a1 = A1[j];
            const float4* w4 = (const float4*)(Wr + j*NL);
            float wv[NL];
            #pragma unroll
            for (int i = 0; i < 6; ++i) {
                float4 w = w4[i];
                wv[4*i+0] = w.x; wv[4*i+1] = w.y; wv[4*i+2] = w.z; wv[4*i+3] = w.w;
            }
            #pragma unroll
            for (int l = 0; l < NL; ++l) {
                acc0[l] = fmaf(a0, wv[l], acc0[l]);
                acc1[l] = fmaf(a1, wv[l], acc1[l]);
            }
        }
        __syncthreads();
    }

    if (ksub >= 8) {
        float* p = Pr + ((ksub-8)*32 + tok)*25;
        float* q = p + 16*25;
        #pragma unroll
        for (int l = 0; l < NL; ++l) { p[l] = acc0[l]; q[l] = acc1[l]; }
    }
    __syncthreads();
    if (ksub < 8) {
        const float* p = Pr + (ksub*32 + tok)*25;
        const float* q = p + 16*25;
        #pragma unroll
        for (int l = 0; l < NL; ++l) { acc0[l] += p[l]; acc1[l] += q[l]; }
    }
    __syncthreads();
    if (ksub < 8) {
        float* p = Pr + (ksub*32 + tok)*25;
        float* q = p + 16*25;
        #pragma unroll
        for (int l = 0; l < NL; ++l) { p[l] = acc0[l]; q[l] = acc1[l]; }
    }
    __syncthreads();

    const int* tm = tlm + b*NS + tile;
    float* Eb = E + (size_t)(b*NS + tile)*NL;
    #pragma unroll
    for (int i = 0; i < 3; ++i) {
        int o = tid + (i << 8);
        int t = o / NL, l = o % NL;
        if (tm[t]) {
            float s = 0.f;
            #pragma unroll
            for (int ks = 0; ks < 8; ++ks)
                s += Pr[(ks*32 + t)*25 + l];
            float x = s + bias[l];
            Eb[t*NL + l] = 1.0f/(1.0f + expf(-x));
        }
    }
}

// ---------------- Kernel B: masked Viterbi decode, one block (256 thr) per batch ----
// Forward on 24 lanes. Per step: phase 1 = 24 back-to-back v_readlane (independent,
// all read sv) | sched_barrier | phase 2 = adds + max3 tree. Grouping pre-satisfies
// the VALU-writes-SGPR -> VALU-reads-SGPR wait states that dominated rounds 2-6.
__global__ __launch_bounds__(256) void ner_viterbi(
    const float* __restrict__ E, const int* __restrict__ tlm,
    const float* __restrict__ trans, const float* __restrict__ st,
    const float* __restrict__ en, int* __restrict__ out)
{
    const int tid = threadIdx.x;
    const int b   = blockIdx.x;
    const int bS  = b*NS;

    __shared__ float Esh[262*NL];           // 25.1 KB (padded: clamp-free prefetch)
    __shared__ float scl[NS*SSTR];          // 28.7 KB score history, stride 28
    __shared__ float Tt[NL*SSTR];           // 2.7 KB  Tt[c*28+p] = T[p][c]
    __shared__ float fin[NL];
    __shared__ unsigned char tr_s[NL][NS];  // 6.1 KB trace[hypothesis][t]
    __shared__ int chosen[NW+2];
    __shared__ int nsh, ltag;

    {
        const float4* src = (const float4*)(E + (size_t)bS*NL);
        float4* dst = (float4*)Esh;
        #pragma unroll
        for (int j = 0; j < 6; ++j) dst[tid + (j << 8)] = src[tid + (j << 8)];
    }
    for (int i = tid; i < NL*NL; i += 256) {
        int c = i / NL, p = i % NL;
        Tt[c*SSTR + p] = trans[p*NL + c];
    }
    if (tid < 64) {   // n = lengths[b]-2 (contiguous prefix mask)
        int a = tlm[bS+tid] + tlm[bS+tid+64] + tlm[bS+tid+128] + tlm[bS+tid+192];
        #pragma unroll
        for (int off = 32; off > 0; off >>= 1) a += __shfl_down(a, off, 64);
        if (tid == 0) nsh = a;
    }
    __syncthreads();
    const int n = nsh;   // 1 <= n <= 254

    // ---- forward: 24 lanes of wave 0 ----
    if (tid < 24) {
        const int c = tid;
        float Tc[NL];
        #pragma unroll
        for (int p = 0; p < NL; ++p) Tc[p] = trans[p*NL + c];

        float sv = st[c] + Esh[c];
        scl[c] = sv;

        auto step = [&](int t, float em) {
            const int svi = __float_as_int(sv);
            int rr[NL];
            #pragma unroll
            for (int p = 0; p < NL; ++p)            // 24 independent readlanes
                rr[p] = __builtin_amdgcn_readlane(svi, p);
            __builtin_amdgcn_sched_barrier(0);      // keep them grouped
            float cand[NL];
            #pragma unroll
            for (int p = 0; p < NL; ++p)
                cand[p] = __int_as_float(rr[p]) + Tc[p];
            float m0 = fmaxf(fmaxf(cand[0],  cand[1]),  cand[2]);
            float m1 = fmaxf(fmaxf(cand[3],  cand[4]),  cand[5]);
            float m2 = fmaxf(fmaxf(cand[6],  cand[7]),  cand[8]);
            float m3 = fmaxf(fmaxf(cand[9],  cand[10]), cand[11]);
            float m4 = fmaxf(fmaxf(cand[12], cand[13]), cand[14]);
            float m5 = fmaxf(fmaxf(cand[15], cand[16]), cand[17]);
            float m6 = fmaxf(fmaxf(cand[18], cand[19]), cand[20]);
            float m7 = fmaxf(fmaxf(cand[21], cand[22]), cand[23]);
            float q0 = fmaxf(fmaxf(m0, m1), m2);
            float q1 = fmaxf(fmaxf(m3, m4), m5);
            float q2 = fmaxf(m6, m7);
            sv = fmaxf(fmaxf(q0, q1), q2) + em;
            scl[t*SSTR + c] = sv;                   // off critical path
        };

        float emb[8];
        #pragma unroll
        for (int j = 0; j < 8; ++j) emb[j] = Esh[(1+j)*NL + c];
        int t0 = 1;
        for (; t0 + 8 <= n; t0 += 8) {
            float emc[8];
            #pragma unroll
            for (int j = 0; j < 8; ++j) emc[j] = emb[j];
            #pragma unroll
            for (int j = 0; j < 8; ++j) emb[j] = Esh[(t0+8+j)*NL + c]; // rows <=261
            #pragma unroll
            for (int j = 0; j < 8; ++j) step(t0 + j, emc[j]);
        }
        for (; t0 < n; ++t0) step(t0, Esh[t0*NL + c]);
        fin[c] = sv + en[c];
    }
    __syncthreads();

    if (tid == 0) {   // argmax(final), first-max tie rule like jnp.argmax
        float bv = fin[0]; int bt = 0;
        #pragma unroll
        for (int cc = 1; cc < 24; ++cc) { if (fin[cc] > bv) { bv = fin[cc]; bt = cc; } }
        ltag = bt;
    }
    __syncthreads();

    // ---- backtrack: NW windows x 24 hypotheses, recompute backpointers ----
    const int K = (n > 1) ? (n - 1 + NW - 1) / NW : 1;
    if (n > 1 && tid < NW*24) {
        const int w = tid / 24 + 1, h = tid % 24;
        int tlo = (w-1)*K; if (tlo > n-1) tlo = n-1;
        int thi = w*K;     if (thi > n-1) thi = n-1;
        int cur = h;
        for (int t = thi; t > tlo; --t) {
            const float4* sp = (const float4*)(scl + (t-1)*SSTR);
            const float4* up = (const float4*)(Tt + cur*SSTR);
            float cand[NL];
            #pragma unroll
            for (int i = 0; i < 6; ++i) {
                float4 s = sp[i], u = up[i];
                cand[4*i+0] = s.x + u.x;     // bitwise-identical to forward cand
                cand[4*i+1] = s.y + u.y;
                cand[4*i+2] = s.z + u.z;
                cand[4*i+3] = s.w + u.w;
            }
            float best = cand[0]; int arg = 0;
            #pragma unroll
            for (int p = 1; p < 24; ++p) { if (cand[p] > best) { best = cand[p]; arg = p; } }
            tr_s[h][t-1] = (unsigned char)arg;
            cur = arg;
        }
    }
    __syncthreads();

    if (tid == 0) {   // stitch windows
        int cur = ltag;
        for (int w = NW; w >= 1; --w) {
            chosen[w] = cur;
            int tlo = (w-1)*K; if (tlo > n-1) tlo = n-1;
            int thi = w*K;     if (thi > n-1) thi = n-1;
            if (thi > tlo) cur = tr_s[cur][tlo];
        }
    }
    __syncthreads();

    {   // emit path: t >= n-1 -> last_tag (identity backpointers on padding)
        const int t = tid;
        int tag;
        if (t >= n-1) tag = ltag;
        else { int w = t / K + 1; tag = tr_s[chosen[w]][t]; }
        out[bS + t] = tag;
    }
}

extern "C" void kernel_launch(void* const* d_in, const int* in_sizes, int n_in,
                              void* d_out, int out_size, void* d_ws, size_t ws_size,
                              hipStream_t stream) {
    const float* tf    = (const float*)d_in[0];
    const int*   tlm   = (const int*)  d_in[2];   // true_label_mask
    const float* W     = (const float*)d_in[3];
    const float* bias  = (const float*)d_in[4];
    const float* trans = (const float*)d_in[5];
    const float* st    = (const float*)d_in[6];
    const float* en    = (const float*)d_in[7];
    float* E = (float*)d_ws;                      // [128,256,24] fp32 = 3.1 MB

    ner_emis<<<dim3(NB*8), dim3(256), 0, stream>>>(tf, tlm, W, bias, E);
    ner_viterbi<<<dim3(NB), dim3(256), 0, stream>>>(E, tlm, trans, st, en, (int*)d_out);
}

// Round 8
// 210.188 us; speedup vs baseline: 1.1366x; 1.0227x over previous
//
#include <hip/hip_runtime.h>
#include <hip/hip_bf16.h>
#include <math.h>

#define NB 128
#define NS 256
#define NH 768
#define NL 24
#define NW 10     // backtrack windows
#define SSTR 28   // scl/Tt row stride (words): 16B-aligned, 8 bank groups

// ---------------- Kernel A: emissions = sigmoid(tf[b,t+1,:] @ W + b) for t < n_b ----
// grid 512 = 128 batches x 4 tiles of 64 tokens; block 512 thr = 8 waves.
// thread = (tok = tid&63, ksub = tid>>6). ksub == wave id -> every W-row read is a
// single-address wave-uniform ds_read_b128 broadcast (cheap); a-reads conflict-free
// (stride 65). DS:VALU ~ 1:3.4 per wave (was ~1:1) -> VALU-bound shape.
__global__ __launch_bounds__(512) void ner_emis(
    const float* __restrict__ tf, const int* __restrict__ tlm,
    const float* __restrict__ W, const float* __restrict__ bias,
    float* __restrict__ E)
{
    const int b    = blockIdx.x >> 2;
    const int tile = (blockIdx.x & 3) << 6;         // token base (64 per tile)
    const int tid  = threadIdx.x;
    if (tlm[b*NS + tile] == 0) return;              // prefix mask: whole tile invalid

    __shared__ float lds[6400];                     // 25.6 KB union
    float* As = lds;                                // [64][65] = 4160 w
    float* Ws = lds + 64*65;                        // [64][24] = 1536 w
    float* Pr = lds;                                // [4][64][25] = 6400 w (after K-loop)

    const int tok  = tid & 63;
    const int ksub = tid >> 6;                      // 0..7 == wave id (uniform per wave)

    float acc[NL];
    #pragma unroll
    for (int l = 0; l < NL; ++l) acc[l] = 0.f;

    const float* tfb = tf + (size_t)(b*NS)*NH;

    for (int kc0 = 0; kc0 < NH; kc0 += 64) {
        // ---- stage A [64 tok][64 k]: 1024 float4 loads, 2/thread, coalesced ----
        #pragma unroll
        for (int i = 0; i < 2; ++i) {
            int idx  = tid + (i << 9);
            int row  = idx >> 4;                    // 0..63
            int c4   = idx & 15;
            int trow = tile + row + 1;              // feature row = token+1
            if (trow > 255) trow = 255;             // clamp (row invalid anyway)
            float4 v = *(const float4*)(tfb + (size_t)trow*NH + kc0 + (c4 << 2));
            float* dst = As + row*65 + (c4 << 2);   // stride 65: banks (tok+k)%32
            dst[0] = v.x; dst[1] = v.y; dst[2] = v.z; dst[3] = v.w;
        }
        // ---- stage W [64 k][24 l]: 384 contiguous float4 ----
        if (tid < 384) ((float4*)Ws)[tid] = ((const float4*)(W + (size_t)kc0*NL))[tid];
        __syncthreads();

        // ---- compute: wave ksub handles k in [8*ksub, 8*ksub+8) ----
        const float* Arow = As + tok*65 + (ksub << 3);
        #pragma unroll
        for (int j = 0; j < 8; ++j) {
            const int k = (ksub << 3) + j;
            float a = Arow[j];                      // conflict-free (2-way) b32
            const float4* w4 = (const float4*)(Ws + k*NL);  // wave-uniform broadcast
            float4 w0 = w4[0], w1 = w4[1], w2 = w4[2];
            acc[0]  = fmaf(a, w0.x, acc[0]);  acc[1]  = fmaf(a, w0.y, acc[1]);
            acc[2]  = fmaf(a, w0.z, acc[2]);  acc[3]  = fmaf(a, w0.w, acc[3]);
            acc[4]  = fmaf(a, w1.x, acc[4]);  acc[5]  = fmaf(a, w1.y, acc[5]);
            acc[6]  = fmaf(a, w1.z, acc[6]);  acc[7]  = fmaf(a, w1.w, acc[7]);
            acc[8]  = fmaf(a, w2.x, acc[8]);  acc[9]  = fmaf(a, w2.y, acc[9]);
            acc[10] = fmaf(a, w2.z, acc[10]); acc[11] = fmaf(a, w2.w, acc[11]);
            float4 w3 = w4[3], w4v = w4[4], w5 = w4[5];
            acc[12] = fmaf(a, w3.x, acc[12]); acc[13] = fmaf(a, w3.y, acc[13]);
            acc[14] = fmaf(a, w3.z, acc[14]); acc[15] = fmaf(a, w3.w, acc[15]);
            acc[16] = fmaf(a, w4v.x, acc[16]); acc[17] = fmaf(a, w4v.y, acc[17]);
            acc[18] = fmaf(a, w4v.z, acc[18]); acc[19] = fmaf(a, w4v.w, acc[19]);
            acc[20] = fmaf(a, w5.x, acc[20]); acc[21] = fmaf(a, w5.y, acc[21]);
            acc[22] = fmaf(a, w5.z, acc[22]); acc[23] = fmaf(a, w5.w, acc[23]);
        }
        __syncthreads();
    }

    // ---- fold 8 ksub slices -> 4 in LDS, then sum 4 ascending at output ----
    if (ksub >= 4) {                                // waves 4..7 publish
        float* p = Pr + ((ksub-4)*64 + tok)*25;
        #pragma unroll
        for (int l = 0; l < NL; ++l) p[l] = acc[l];
    }
    __syncthreads();
    if (ksub < 4) {                                 // waves 0..3 merge (lo+hi)
        const float* p = Pr + (ksub*64 + tok)*25;
        #pragma unroll
        for (int l = 0; l < NL; ++l) acc[l] += p[l];
    }
    __syncthreads();
    if (ksub < 4) {                                 // publish merged slices
        float* p = Pr + (ksub*64 + tok)*25;
        #pragma unroll
        for (int l = 0; l < NL; ++l) p[l] = acc[l];
    }
    __syncthreads();

    const int* tm = tlm + b*NS + tile;
    float* Eb = E + (size_t)(b*NS + tile)*NL;
    #pragma unroll
    for (int i = 0; i < 3; ++i) {
        int o = tid + (i << 9);                     // 0..1535 (64 tok x 24 lab)
        int t = o / NL, l = o % NL;
        if (tm[t]) {
            float s = ((Pr[(0*64 + t)*25 + l] + Pr[(1*64 + t)*25 + l])
                     +  Pr[(2*64 + t)*25 + l]) + Pr[(3*64 + t)*25 + l];
            float x = s + bias[l];
            Eb[t*NL + l] = 1.0f/(1.0f + expf(-x));
        }
    }
}

// ---------------- Kernel B: masked Viterbi decode, one block (256 thr) per batch ----
// Forward on 24 lanes; broadcast via LDS round-trip: ds_write_b32 sbc[c] then six
// broadcast ds_read_b128 (same-wave DS ops are in-order). Probes the lone-wave
// readlane-stream stall theory (readlane variants measured ~425 cyc/step).
__global__ __launch_bounds__(256) void ner_viterbi(
    const float* __restrict__ E, const int* __restrict__ tlm,
    const float* __restrict__ trans, const float* __restrict__ st,
    const float* __restrict__ en, int* __restrict__ out)
{
    const int tid = threadIdx.x;
    const int b   = blockIdx.x;
    const int bS  = b*NS;

    __shared__ float Esh[262*NL];           // 25.1 KB (padded: clamp-free prefetch)
    __shared__ float scl[NS*SSTR];          // 28.7 KB score history, stride 28
    __shared__ float Tt[NL*SSTR];           // 2.7 KB  Tt[c*28+p] = T[p][c]
    __shared__ float fin[NL];
    __shared__ __align__(16) float sbc[32]; // broadcast scratch
    __shared__ unsigned char tr_s[NL][NS];  // 6.1 KB trace[hypothesis][t]
    __shared__ int chosen[NW+2];
    __shared__ int nsh, ltag;

    {
        const float4* src = (const float4*)(E + (size_t)bS*NL);
        float4* dst = (float4*)Esh;
        #pragma unroll
        for (int j = 0; j < 6; ++j) dst[tid + (j << 8)] = src[tid + (j << 8)];
    }
    for (int i = tid; i < NL*NL; i += 256) {
        int c = i / NL, p = i % NL;
        Tt[c*SSTR + p] = trans[p*NL + c];
    }
    if (tid < 64) {   // n = lengths[b]-2 (contiguous prefix mask)
        int a = tlm[bS+tid] + tlm[bS+tid+64] + tlm[bS+tid+128] + tlm[bS+tid+192];
        #pragma unroll
        for (int off = 32; off > 0; off >>= 1) a += __shfl_down(a, off, 64);
        if (tid == 0) nsh = a;
    }
    __syncthreads();
    const int n = nsh;   // 1 <= n <= 254

    // ---- forward: 24 lanes of wave 0 ----
    if (tid < 24) {
        const int c = tid;
        float Tc[NL];
        #pragma unroll
        for (int p = 0; p < NL; ++p) Tc[p] = trans[p*NL + c];

        float sv = st[c] + Esh[c];
        scl[c] = sv;
        const float4* sb4 = (const float4*)sbc;

        auto step = [&](int t, float em) {
            sbc[c] = sv;                            // 24 lanes, banks 0..23: 1 ds_write
            float4 s0 = sb4[0], s1 = sb4[1], s2 = sb4[2],
                   s3 = sb4[3], s4 = sb4[4], s5 = sb4[5];   // 6 broadcast b128
            float cand[NL];
            cand[0]  = s0.x + Tc[0];  cand[1]  = s0.y + Tc[1];
            cand[2]  = s0.z + Tc[2];  cand[3]  = s0.w + Tc[3];
            cand[4]  = s1.x + Tc[4];  cand[5]  = s1.y + Tc[5];
            cand[6]  = s1.z + Tc[6];  cand[7]  = s1.w + Tc[7];
            cand[8]  = s2.x + Tc[8];  cand[9]  = s2.y + Tc[9];
            cand[10] = s2.z + Tc[10]; cand[11] = s2.w + Tc[11];
            cand[12] = s3.x + Tc[12]; cand[13] = s3.y + Tc[13];
            cand[14] = s3.z + Tc[14]; cand[15] = s3.w + Tc[15];
            cand[16] = s4.x + Tc[16]; cand[17] = s4.y + Tc[17];
            cand[18] = s4.z + Tc[18]; cand[19] = s4.w + Tc[19];
            cand[20] = s5.x + Tc[20]; cand[21] = s5.y + Tc[21];
            cand[22] = s5.z + Tc[22]; cand[23] = s5.w + Tc[23];
            float m0 = fmaxf(fmaxf(cand[0],  cand[1]),  cand[2]);
            float m1 = fmaxf(fmaxf(cand[3],  cand[4]),  cand[5]);
            float m2 = fmaxf(fmaxf(cand[6],  cand[7]),  cand[8]);
            float m3 = fmaxf(fmaxf(cand[9],  cand[10]), cand[11]);
            float m4 = fmaxf(fmaxf(cand[12], cand[13]), cand[14]);
            float m5 = fmaxf(fmaxf(cand[15], cand[16]), cand[17]);
            float m6 = fmaxf(fmaxf(cand[18], cand[19]), cand[20]);
            float m7 = fmaxf(fmaxf(cand[21], cand[22]), cand[23]);
            float q0 = fmaxf(fmaxf(m0, m1), m2);
            float q1 = fmaxf(fmaxf(m3, m4), m5);
            float q2 = fmaxf(m6, m7);
            sv = fmaxf(fmaxf(q0, q1), q2) + em;
            scl[t*SSTR + c] = sv;                   // off critical path
        };

        float emb[8];
        #pragma unroll
        for (int j = 0; j < 8; ++j) emb[j] = Esh[(1+j)*NL + c];
        int t0 = 1;
        for (; t0 + 8 <= n; t0 += 8) {
            float emc[8];
            #pragma unroll
            for (int j = 0; j < 8; ++j) emc[j] = emb[j];
            #pragma unroll
            for (int j = 0; j < 8; ++j) emb[j] = Esh[(t0+8+j)*NL + c]; // rows <=261
            #pragma unroll
            for (int j = 0; j < 8; ++j) step(t0 + j, emc[j]);
        }
        for (; t0 < n; ++t0) step(t0, Esh[t0*NL + c]);
        fin[c] = sv + en[c];
    }
    __syncthreads();

    if (tid == 0) {   // argmax(final), first-max tie rule like jnp.argmax
        float bv = fin[0]; int bt = 0;
        #pragma unroll
        for (int cc = 1; cc < 24; ++cc) { if (fin[cc] > bv) { bv = fin[cc]; bt = cc; } }
        ltag = bt;
    }
    __syncthreads();

    // ---- backtrack: NW windows x 24 hypotheses, recompute backpointers ----
    const int K = (n > 1) ? (n - 1 + NW - 1) / NW : 1;
    if (n > 1 && tid < NW*24) {
        const int w = tid / 24 + 1, h = tid % 24;
        int tlo = (w-1)*K; if (tlo > n-1) tlo = n-1;
        int thi = w*K;     if (thi > n-1) thi = n-1;
        int cur = h;
        for (int t = thi; t > tlo; --t) {
            const float4* sp = (const float4*)(scl + (t-1)*SSTR);
            const float4* up = (const float4*)(Tt + cur*SSTR);
            float cand[NL];
            #pragma unroll
            for (int i = 0; i < 6; ++i) {
                float4 s = sp[i], u = up[i];
                cand[4*i+0] = s.x + u.x;     // bitwise-identical to forward cand
                cand[4*i+1] = s.y + u.y;
                cand[4*i+2] = s.z + u.z;
                cand[4*i+3] = s.w + u.w;
            }
            float best = cand[0]; int arg = 0;
            #pragma unroll
            for (int p = 1; p < 24; ++p) { if (cand[p] > best) { best = cand[p]; arg = p; } }
            tr_s[h][t-1] = (unsigned char)arg;
            cur = arg;
        }
    }
    __syncthreads();

    if (tid == 0) {   // stitch windows
        int cur = ltag;
        for (int w = NW; w >= 1; --w) {
            chosen[w] = cur;
            int tlo = (w-1)*K; if (tlo > n-1) tlo = n-1;
            int thi = w*K;     if (thi > n-1) thi = n-1;
            if (thi > tlo) cur = tr_s[cur][tlo];
        }
    }
    __syncthreads();

    {   // emit path: t >= n-1 -> last_tag (identity backpointers on padding)
        const int t = tid;
        int tag;
        if (t >= n-1) tag = ltag;
        else { int w = t / K + 1; tag = tr_s[chosen[w]][t]; }
        out[bS + t] = tag;
    }
}

extern "C" void kernel_launch(void* const* d_in, const int* in_sizes, int n_in,
                              void* d_out, int out_size, void* d_ws, size_t ws_size,
                              hipStream_t stream) {
    const float* tf    = (const float*)d_in[0];
    const int*   tlm   = (const int*)  d_in[2];   // true_label_mask
    const float* W     = (const float*)d_in[3];
    const float* bias  = (const float*)d_in[4];
    const float* trans = (const float*)d_in[5];
    const float* st    = (const float*)d_in[6];
    const float* en    = (const float*)d_in[7];
    float* E = (float*)d_ws;                      // [128,256,24] fp32 = 3.1 MB

    ner_emis<<<dim3(NB*4), dim3(512), 0, stream>>>(tf, tlm, W, bias, E);
    ner_viterbi<<<dim3(NB), dim3(256), 0, stream>>>(E, tlm, trans, st, en, (int*)d_out);
}